// Round 1
// baseline (41.378 us; speedup 1.0000x reference)
//
#include <hip/hip_runtime.h>
#include <hip/hip_bf16.h>

// ExtraMSAEmbedding: out[p, o] = W[o, msa[p]] + hd[p]*W[o,23] + dv[p]*W[o,24] + b[o]
// p = flattened (seq, res) position, 2048*384 = 786432 positions, o in [0,64).
// Write-bound: 201 MB f32 output vs ~9.4 MB input reads.

#define C_IN  25
#define C_OUT 64

__global__ __launch_bounds__(256) void extra_msa_emb_kernel(
    const int* __restrict__ msa,
    const float* __restrict__ hd,
    const float* __restrict__ dv,
    const float* __restrict__ W,   // [64, 25] row-major
    const float* __restrict__ b,   // [64]
    float* __restrict__ out,       // [npos, 64]
    int npos) {
    // Fused table, transposed: T[c][o] = W[o*25+c] (+ b[o] when c < 23).
    // Transposed layout -> reads along o are consecutive addresses (bank-clean).
    __shared__ float T[C_IN][C_OUT];
    const int tid = threadIdx.x;
    for (int idx = tid; idx < C_IN * C_OUT; idx += 256) {
        const int c = idx >> 6;      // idx / 64
        const int o = idx & 63;      // idx % 64
        float v = W[o * C_IN + c];
        if (c < 23) v += b[o];
        T[c][o] = v;
    }
    __syncthreads();

    const int group = tid >> 4;   // 16 positions per block-iteration
    const int lane  = tid & 15;   // 16 threads per position
    const int o     = lane * 4;   // each thread owns 4 consecutive outputs

    const float4 w23 = *reinterpret_cast<const float4*>(&T[23][o]);
    const float4 w24 = *reinterpret_cast<const float4*>(&T[24][o]);

    // npos (786432) is divisible by 16, so no tail handling needed.
    for (long long base = (long long)blockIdx.x * 16; base < npos;
         base += (long long)gridDim.x * 16) {
        const int p = (int)base + group;
        const int cls = msa[p];           // in [0, 23)
        const float h = hd[p];
        const float d = dv[p];

        const float4 t = *reinterpret_cast<const float4*>(&T[cls][o]);
        float4 r;
        r.x = t.x + h * w23.x + d * w24.x;
        r.y = t.y + h * w23.y + d * w24.y;
        r.z = t.z + h * w23.z + d * w24.z;
        r.w = t.w + h * w23.w + d * w24.w;

        *reinterpret_cast<float4*>(&out[(long long)p * C_OUT + o]) = r;
    }
}

extern "C" void kernel_launch(void* const* d_in, const int* in_sizes, int n_in,
                              void* d_out, int out_size, void* d_ws, size_t ws_size,
                              hipStream_t stream) {
    const int*   msa = (const int*)d_in[0];
    const float* hd  = (const float*)d_in[1];
    const float* dv  = (const float*)d_in[2];
    const float* W   = (const float*)d_in[3];
    const float* b   = (const float*)d_in[4];
    float* out = (float*)d_out;

    const int npos = in_sizes[0];  // 2048 * 384 = 786432

    const int block = 256;
    const int grid  = 4096;  // grid-stride: each block covers 12 chunks of 16 positions
    extra_msa_emb_kernel<<<grid, block, 0, stream>>>(msa, hd, dv, W, b, out, npos);
}

// Round 2
// 37.371 us; speedup vs baseline: 1.1072x; 1.1072x over previous
//
#include <hip/hip_runtime.h>
#include <hip/hip_bf16.h>

// ExtraMSAEmbedding: out[p, o] = W[o, msa[p]] + hd[p]*W[o,23] + dv[p]*W[o,24] + b[o]
// p = flattened (seq, res) position, 2048*384 = 786432 positions, o in [0,64).
// Write-bound: 201 MB f32 output vs ~9.4 MB input reads. Fill-kernel ceiling ~7 TB/s.

#define C_IN   25
#define C_OUT  64
#define TPAD   68   // row stride in floats: 272 B, 16B-aligned, breaks 256B bank period
#define UNROLL 4

typedef float v4f __attribute__((ext_vector_type(4)));

__global__ __launch_bounds__(256) void extra_msa_emb_kernel(
    const int* __restrict__ msa,
    const float* __restrict__ hd,
    const float* __restrict__ dv,
    const float* __restrict__ W,   // [64, 25] row-major
    const float* __restrict__ b,   // [64]
    float* __restrict__ out,       // [npos, 64]
    int npos) {
    // Fused table, transposed + padded: T[c][o] = W[o*25+c] (+ b[o] when c < 23).
    __shared__ float T[C_IN][TPAD];
    const int tid = threadIdx.x;
    for (int idx = tid; idx < C_IN * C_OUT; idx += 256) {
        const int c = idx >> 6;      // idx / 64
        const int o = idx & 63;      // idx % 64
        float v = W[o * C_IN + c];
        if (c < 23) v += b[o];
        T[c][o] = v;
    }
    __syncthreads();

    const int group = tid >> 4;   // 16 groups per block; wave w = groups 4w..4w+3
    const int lane  = tid & 15;   // 16 threads per position
    const int o     = lane * 4;   // each thread owns 4 consecutive outputs

    const v4f w23 = *reinterpret_cast<const v4f*>(&T[23][o]);
    const v4f w24 = *reinterpret_cast<const v4f*>(&T[24][o]);

    // Each block-iteration covers 64 positions: position = base + j*16 + group.
    // Wave w at unroll j stores positions {base+j*16+4w .. +3} -> contiguous 1 KB.
    // npos = 786432 is divisible by 64, so chunks are always complete.
    for (long long base = (long long)blockIdx.x * 64; base < npos;
         base += (long long)gridDim.x * 64) {
        const int pbase = (int)base + group;

        int   cls[UNROLL];
        float h[UNROLL], d[UNROLL];
#pragma unroll
        for (int j = 0; j < UNROLL; ++j) {
            const int p = pbase + j * 16;
            cls[j] = msa[p];
            h[j]   = hd[p];
            d[j]   = dv[p];
        }

        v4f t[UNROLL];
#pragma unroll
        for (int j = 0; j < UNROLL; ++j)
            t[j] = *reinterpret_cast<const v4f*>(&T[cls[j]][o]);

#pragma unroll
        for (int j = 0; j < UNROLL; ++j) {
            v4f r = t[j] + h[j] * w23 + d[j] * w24;
            const long long p = (long long)(pbase + j * 16);
            __builtin_nontemporal_store(r, reinterpret_cast<v4f*>(&out[p * C_OUT + o]));
        }
    }
}

extern "C" void kernel_launch(void* const* d_in, const int* in_sizes, int n_in,
                              void* d_out, int out_size, void* d_ws, size_t ws_size,
                              hipStream_t stream) {
    const int*   msa = (const int*)d_in[0];
    const float* hd  = (const float*)d_in[1];
    const float* dv  = (const float*)d_in[2];
    const float* W   = (const float*)d_in[3];
    const float* b   = (const float*)d_in[4];
    float* out = (float*)d_out;

    const int npos = in_sizes[0];  // 2048 * 384 = 786432

    const int block = 256;
    const int grid  = 4096;  // 64 positions/block-iter -> 3 grid-stride iterations
    extra_msa_emb_kernel<<<grid, block, 0, stream>>>(msa, hd, dv, W, b, out, npos);
}